// Round 8
// baseline (258.061 us; speedup 1.0000x reference)
//
#include <hip/hip_runtime.h>

typedef unsigned int u32;
typedef unsigned long long u64;
typedef unsigned short u16;

#define NS    8192
#define NQ    16384
#define DD    128
#define TOPK  32
#define RR    16

// --- MFMA-filter sim parameters ---
#define TM2   32       // rows per simA block
#define TAUF  0.1685f  // approx filter threshold (exact TAU=0.17; ~15 sigma margin vs bf16 err)
#define HC2   192      // fallback: per-half candidate cap
#define CSTR  196      // fallback: cand row stride (u32s)
#define KP2   40       // approx-top-K' target (needs 32; 8-rank margin)
#define CAPW  96       // fallback survivor cap
#define BASEK 0x3E2C8000u  // float bits floor of TAUF-masked keys
#define SEGC  28       // per-(row,quarter,wave) segment cap (lambda=7.25, +7.7 sigma)
#define SEGN  8        // waves per simA block
#define SEGQ  2        // quarters per half
#define SEGH  (SEGN * SEGQ)    // 16 segments per row-half
#define SEGSH (SEGC * SEGH)    // 448 slots per row-half
#define WS_NEED ((size_t)(16384 * SEGSH + 16384 * SEGH) * 4)

typedef float f32x4 __attribute__((ext_vector_type(4)));
typedef short short8v __attribute__((ext_vector_type(8)));

__device__ __forceinline__ u64 packvj(float v, int j) {
    return ((u64)__float_as_uint(v) << 32) | (u32)j;   // v>0 -> u64 order == (v, j) lex
}

__device__ __forceinline__ int keybin(u32 key) {
    u32 b = (key - BASEK) >> 19;                       // 128 bins, monotone in key
    return (b > 127u) ? 127 : (int)b;
}

// ---------- prep: numpy-exact norms; row-major exact x_row + bf16 copy -----
__global__ __launch_bounds__(256) void prep_kernel(const float* __restrict__ s_emb,
                                                   float* __restrict__ x_row,
                                                   u16* __restrict__ xbf) {
    __shared__ float tile[64][129];
    __shared__ float nrm[64];
    const int row0 = blockIdx.x * 64;
    const int tid = threadIdx.x;
    for (int it = 0; it < 32; ++it) {
        int idx = it * 256 + tid;
        int rr = idx >> 7, cc = idx & 127;
        tile[rr][cc] = s_emb[(size_t)(row0 + rr) * DD + cc];
    }
    __syncthreads();
    if (tid < 64) {
        float r8[8];
#pragma unroll
        for (int c = 0; c < 8; ++c) { float v = tile[tid][c]; r8[c] = __fmul_rn(v, v); }
        for (int m = 1; m < 16; ++m) {
#pragma unroll
            for (int c = 0; c < 8; ++c) {
                float v = tile[tid][8 * m + c];
                r8[c] = __fadd_rn(r8[c], __fmul_rn(v, v));
            }
        }
        float res = __fadd_rn(
            __fadd_rn(__fadd_rn(r8[0], r8[1]), __fadd_rn(r8[2], r8[3])),
            __fadd_rn(__fadd_rn(r8[4], r8[5]), __fadd_rn(r8[6], r8[7])));
        nrm[tid] = __fsqrt_rn(res);
    }
    __syncthreads();
    for (int m = 0; m < 32; ++m) {
        int idx = m * 256 + tid;
        int rr = idx >> 7, k = idx & 127;
        float v = __fdiv_rn(tile[rr][k], nrm[rr]);     // same bits as old x_t values
        x_row[(size_t)(row0 + rr) * DD + k] = v;
        u32 b = __float_as_uint(v);                    // bf16 RNE
        xbf[(size_t)(row0 + rr) * DD + k] = (u16)((b + 0x7fffu + ((b >> 16) & 1u)) >> 16);
    }
}

// ---------- proto partial sums: 64 blocks x 128 rows ------------------------
__global__ __launch_bounds__(256) void proto_part_kernel(const float* __restrict__ s_emb,
                                                         double* __restrict__ part) {
    __shared__ double ps[256];
    const int b = blockIdx.x;
    const int h = b >> 5, seg = b & 31;
    const int tid = threadIdx.x;
    const int sub = tid >> 7, d = tid & 127;
    const size_t row0 = (size_t)h * 4096 + (size_t)seg * 128 + (size_t)sub * 64;
    double acc = 0.0;
    for (int r = 0; r < 64; ++r)
        acc += (double)s_emb[(row0 + r) * DD + d];
    ps[tid] = acc;
    __syncthreads();
    if (sub == 0) part[(size_t)b * DD + d] = ps[d] + ps[128 + d];
}

// ---------- combine partials -> prototypes -> K,V (kv = 512 floats) --------
__global__ __launch_bounds__(256) void kv_kernel(
    const double* __restrict__ part,
    const float* __restrict__ Wk, const float* __restrict__ bk,
    const float* __restrict__ Wv, const float* __restrict__ bv,
    float* __restrict__ kv) {
    __shared__ double prd[2][DD];
    const int tid = threadIdx.x;
    const int j = tid >> 7, d = tid & 127;
    {
        const int h = (j == 0) ? 1 : 0;
        double s = 0.0;
        for (int b = 0; b < 32; ++b) s += part[(size_t)(h * 32 + b) * DD + d];
        prd[j][d] = s * (1.0 / 4096.0);
    }
    __syncthreads();
    double ka = (double)bk[d], va = (double)bv[d];
    for (int e = 0; e < DD; ++e) {
        double p = prd[j][e];
        ka += p * (double)Wk[d * DD + e];
        va += p * (double)Wv[d * DD + e];
    }
    kv[j * DD + d]          = (float)ka;
    kv[2 * DD + j * DD + d] = (float)va;
}

// ---------- simA: MFMA filter over 32 rows x 2048 cols (quarter-half) -------
// Grid 1024 blocks (4/CU). 8 waves x 256 cols. Ballot-prefix LDS insert,
// coalesced dump. Segment = (row, half, quarter, wave) cap SEGC.
__global__ __launch_bounds__(512) void simA_kernel(
    const u16* __restrict__ xbf, u32* __restrict__ wsk, u32* __restrict__ wsc) {
    __shared__ u32 seg[TM2 * SEGN * SEGC];              // 28,672 B, flat [row][wv][slot]
    const int tid = threadIdx.x;
    const int g = blockIdx.x >> 2;
    const int h = (blockIdx.x >> 1) & 1;
    const int q = blockIdx.x & 1;
    const int i0 = g * TM2;

    const int lane = tid & 63;
    const int wv = tid >> 6;                            // 0..7
    const int l15 = lane & 15, l4 = lane >> 4;
    const int rb = l4 << 2;
    const u32 lowm = (1u << l15) - 1u;

    short8v a[2][4];
#pragma unroll
    for (int mt = 0; mt < 2; ++mt) {
        const u16* xa = xbf + (size_t)(i0 + mt * 16 + l15) * DD + (l4 << 3);
#pragma unroll
        for (int kk = 0; kk < 4; ++kk)
            a[mt][kk] = *(const short8v*)(xa + kk * 32);
    }

    int sb[8];
#pragma unroll
    for (int p = 0; p < 4; ++p) {
        sb[p]     = ((rb + p) * SEGN + wv) * SEGC;
        sb[p + 4] = ((16 + rb + p) * SEGN + wv) * SEGC;
    }
    u32 count[8];
#pragma unroll
    for (int p = 0; p < 8; ++p) count[p] = 0;

    const int jw = h * 4096 + q * 2048 + wv * 256;      // global col of this wave's tile
    const u32 j12b = (u32)(q * 2048 + wv * 256);        // within-half base
    const u16* xbp = xbf + (size_t)(jw + l15) * DD + (l4 << 3);
    short8v b0 = *(const short8v*)(xbp);
    short8v b1 = *(const short8v*)(xbp + 32);
    short8v b2 = *(const short8v*)(xbp + 64);
    short8v b3 = *(const short8v*)(xbp + 96);
    for (int nt = 0; nt < 16; ++nt) {
        short8v c0 = b0, c1 = b1, c2 = b2, c3 = b3;
        if (nt < 15) {                                  // prefetch next 16-col tile
            xbp += 16 * DD;
            b0 = *(const short8v*)(xbp);
            b1 = *(const short8v*)(xbp + 32);
            b2 = *(const short8v*)(xbp + 64);
            b3 = *(const short8v*)(xbp + 96);
        }
        f32x4 acc0 = {0.f, 0.f, 0.f, 0.f}, acc1 = {0.f, 0.f, 0.f, 0.f};
        acc0 = __builtin_amdgcn_mfma_f32_16x16x32_bf16(a[0][0], c0, acc0, 0, 0, 0);
        acc1 = __builtin_amdgcn_mfma_f32_16x16x32_bf16(a[1][0], c0, acc1, 0, 0, 0);
        acc0 = __builtin_amdgcn_mfma_f32_16x16x32_bf16(a[0][1], c1, acc0, 0, 0, 0);
        acc1 = __builtin_amdgcn_mfma_f32_16x16x32_bf16(a[1][1], c1, acc1, 0, 0, 0);
        acc0 = __builtin_amdgcn_mfma_f32_16x16x32_bf16(a[0][2], c2, acc0, 0, 0, 0);
        acc1 = __builtin_amdgcn_mfma_f32_16x16x32_bf16(a[1][2], c2, acc1, 0, 0, 0);
        acc0 = __builtin_amdgcn_mfma_f32_16x16x32_bf16(a[0][3], c3, acc0, 0, 0, 0);
        acc1 = __builtin_amdgcn_mfma_f32_16x16x32_bf16(a[1][3], c3, acc1, 0, 0, 0);

        const u32 j12 = j12b + (u32)(nt * 16 + l15);    // within-half index, 12 bits
#pragma unroll
        for (int p = 0; p < 4; ++p) {                   // C/D: col=lane&15, row=(lane>>4)*4+p
            {
                float v = acc0[p];
                bool pass = v >= TAUF;
                u64 m = __ballot(pass);
                u32 gm = (u32)(m >> (l4 << 4)) & 0xffffu;
                u32 off = count[p] + (u32)__popc(gm & lowm);
                if (pass && off < SEGC)
                    seg[sb[p] + off] = (__float_as_uint(v) & 0xfffff000u) | j12;
                count[p] += (u32)__popc(gm);
            }
            {
                float v = acc1[p];
                bool pass = v >= TAUF;
                u64 m = __ballot(pass);
                u32 gm = (u32)(m >> (l4 << 4)) & 0xffffu;
                u32 off = count[p + 4] + (u32)__popc(gm & lowm);
                if (pass && off < SEGC)
                    seg[sb[p + 4] + off] = (__float_as_uint(v) & 0xfffff000u) | j12;
                count[p + 4] += (u32)__popc(gm);
            }
        }
    }
    __syncthreads();

    if (l15 == 0) {
#pragma unroll
        for (int p = 0; p < 8; ++p) {
            int rl = (p < 4) ? (rb + p) : (16 + rb + (p - 4));
            wsc[((size_t)(h * 8192 + i0 + rl) << 4) + q * 8 + wv] = count[p];
        }
    }
    // coalesced dump: 896B runs per (row, quarter)
    for (u32 u = tid; u < TM2 * SEGN * SEGC; u += 512) {
        u32 rr = u / (SEGN * SEGC);
        u32 off = u - rr * (SEGN * SEGC);
        wsk[(size_t)(h * 8192 + i0 + rr) * SEGSH + q * (SEGN * SEGC) + off] = seg[u];
    }
}

// ---------- simB: one WAVE per row, register-resident selection -------------
// Load 896 slots (2 halves x 16 segs x 28) into 14 VGPRs (count-masked),
// uniform binary search via ballot counts -> threshold with count in [40,64],
// ballot-prefix compact (<=64 -> one per lane), per-lane exact ascending fmaf
// chain, rank among 64 lanes -> top-32, j-rank sort -> lists32.
__global__ __launch_bounds__(256) void simB_kernel(
    const float* __restrict__ x_row, const u32* __restrict__ wsk,
    const u32* __restrict__ wsc, u32* __restrict__ lists32) {
    __shared__ float xi[4][DD];                        // own row (broadcast reads)
    __shared__ u32 sj[4][64];                          // survivor j (global 0..8191)
    __shared__ u64 vals[4][64];                        // exact packed values
    __shared__ u32 win[4][TOPK];

    const int tid = threadIdx.x;
    const int w = tid >> 6, lane = tid & 63;
    const int row = blockIdx.x * 4 + w;

    xi[w][lane] = x_row[(size_t)row * DD + lane];
    xi[w][64 + lane] = x_row[(size_t)row * DD + 64 + lane];
    if (lane < TOPK) win[w][lane] = 0u;

    // segment counts (2 halves x 16 segments), clamped
    int cw[32];
#pragma unroll
    for (int hw = 0; hw < 32; ++hw) {
        u32 c = wsc[((size_t)((hw >> 4) * 8192 + row) << 4) + (hw & 15)];
        cw[hw] = (c < (u32)SEGC) ? (int)c : SEGC;
    }

    // load all slots; invalid -> 0
    u32 k[14];
#pragma unroll
    for (int hh = 0; hh < 2; ++hh) {
        const u32* kb = wsk + (size_t)(hh * 8192 + row) * SEGSH;
#pragma unroll
        for (int qq = 0; qq < 7; ++qq) {
            int idx = qq * 64 + lane;                   // 0..447
            u32 key = kb[idx];
            int wv16 = (idx * 2341) >> 16;              // idx/28 for idx<448
            int s = idx - wv16 * 28;
            if (s >= cw[hh * 16 + wv16]) key = 0;
            k[hh * 7 + qq] = key;
        }
    }

    // n = total valid keys
    int n = 0;
#pragma unroll
    for (int q = 0; q < 14; ++q) n += __popcll(__ballot(k[q] != 0));

    // threshold T: count(key >= T) in [min(n,40), 64]
    u32 T = 1u;
    if (n > 64) {
        u32 lo = BASEK, hi = 0x40000000u;               // count(>=lo)=n>=40, count(>=hi)=0<40
        for (int it = 0; it < 28; ++it) {
            u32 mid = (lo + hi) >> 1;
            int c = 0;
#pragma unroll
            for (int q = 0; q < 14; ++q) c += __popcll(__ballot(k[q] >= mid));
            if (c >= KP2) {
                lo = mid;
                if (c <= 64) break;                     // in window
            } else {
                hi = mid;
            }
            if (hi - lo <= 1) break;                    // collapsed: count(>=lo) ~= 40
        }
        T = lo;
    }

    // compact survivors (<= 64)
    int base = 0;
#pragma unroll
    for (int q = 0; q < 14; ++q) {
        bool pass = (k[q] >= T) && (k[q] != 0);
        u64 m = __ballot(pass);
        int pos = base + __popcll(m & ((1ull << lane) - 1ull));
        if (pass) sj[w][pos] = (u32)((q >= 7) << 12) | (k[q] & 0xfffu);
        base += __popcll(m);
    }
    const int mcnt = (base < 64) ? base : 64;

    // exact recompute: bit-identical ascending fmaf chain per lane
    u64 mine = 0;
    if (lane < mcnt) {
        int j = (int)sj[w][lane];
        const float4* xj = (const float4*)(x_row + (size_t)j * DD);
        const float* xir = xi[w];
        float s = 0.f;
#pragma unroll 4
        for (int kb = 0; kb < 32; ++kb) {
            float4 p4 = xj[kb];
            s = fmaf(xir[kb * 4 + 0], p4.x, s);
            s = fmaf(xir[kb * 4 + 1], p4.y, s);
            s = fmaf(xir[kb * 4 + 2], p4.z, s);
            s = fmaf(xir[kb * 4 + 3], p4.w, s);
        }
        mine = packvj(s, j);
    }
    vals[w][lane] = mine;

    // rank among 64 (u64 desc; broadcast LDS reads, wave-local ordering)
    int rank = 0;
#pragma unroll 8
    for (int q = 0; q < 64; ++q) rank += (vals[w][q] > mine);
    if (mine && rank < TOPK) win[w][rank] = (u32)mine;  // low 32 bits = j

    // order by j ascending via j-rank; write final u32 list (stride 128)
    if (lane < TOPK) {
        u32 jv = win[w][lane];
        int s2 = 0;
#pragma unroll
        for (int q = 0; q < TOPK; ++q) s2 += (win[w][q] < jv);
        lists32[(size_t)row * 128 + s2] = jv;
    }
}

// ---------- aggregation + epilogue (reads j-sorted u32 lists) ---------------
__global__ __launch_bounds__(256) void agg_kernel(
    const float* __restrict__ s_emb, const u32* __restrict__ lists32,
    const float* __restrict__ alpha_p, float* __restrict__ out_s) {
    __shared__ int wj[RR][TOPK];
    const int i0 = blockIdx.x * RR;
    const int tid = threadIdx.x;
    for (int u = tid; u < RR * TOPK; u += 256) {
        int rr = u >> 5, w = u & 31;
        wj[rr][w] = (int)lists32[(size_t)(i0 + rr) * 128 + w];
    }
    __syncthreads();

    const float alpha = alpha_p[0];
    const int d = tid & 127;
    for (int rp = 0; rp < 8; ++rp) {
        const int rw = rp * 2 + (tid >> 7);
        float a = 0.0f;
        for (int w = 0; w < TOPK; ++w)
            a = __fadd_rn(a, s_emb[(size_t)wj[rw][w] * DD + d]);
        float base = s_emb[(size_t)(i0 + rw) * DD + d];
        out_s[(size_t)(i0 + rw) * DD + d] = __fadd_rn(base, __fmul_rn(alpha, a));
    }
}

// ---------- fallback fused sim kernel (used when ws too small) --------------
__global__ __launch_bounds__(512, 4) void simf_kernel(
    const float* __restrict__ x_row, const u16* __restrict__ xbf,
    u64* __restrict__ lists) {
    __shared__ __align__(16) u32 cand[TM2][CSTR];
    __shared__ __align__(16) u32 surv[TM2][CAPW];
    __shared__ u32 hist[TM2][64];
    __shared__ float xi[TM2][DD + 4];
    __shared__ int cnt[TM2];
    __shared__ int scnt[TM2];

    const int tid = threadIdx.x;
    const int g = blockIdx.x >> 1, h = blockIdx.x & 1;
    const int i0 = g * TM2;
    const int jbase = h * 4096;

    if (tid < TM2) { cnt[tid] = 0; scnt[tid] = 0; }
    for (int u = tid; u < TM2 * 64; u += 512) ((u32*)hist)[u] = 0;
    for (int u = tid; u < TM2 * DD; u += 512) {
        int r = u >> 7, k = u & 127;
        xi[r][k] = x_row[(size_t)(i0 + r) * DD + k];
    }
    __syncthreads();

    const int lane = tid & 63;
    const int wv = tid >> 6;
    const int l15 = lane & 15, l4 = lane >> 4;

    short8v a[2][4];
#pragma unroll
    for (int mt = 0; mt < 2; ++mt) {
        const u16* xa = xbf + (size_t)(i0 + mt * 16 + l15) * DD + (l4 << 3);
#pragma unroll
        for (int kk = 0; kk < 4; ++kk)
            a[mt][kk] = *(const short8v*)(xa + kk * 32);
    }

    const int jw = jbase + wv * 512;
    const u16* xbp = xbf + (size_t)(jw + l15) * DD + (l4 << 3);
    short8v b0 = *(const short8v*)(xbp);
    short8v b1 = *(const short8v*)(xbp + 32);
    short8v b2 = *(const short8v*)(xbp + 64);
    short8v b3 = *(const short8v*)(xbp + 96);
    for (int nt = 0; nt < 32; ++nt) {
        short8v c0 = b0, c1 = b1, c2 = b2, c3 = b3;
        if (nt < 31) {
            xbp += 16 * DD;
            b0 = *(const short8v*)(xbp);
            b1 = *(const short8v*)(xbp + 32);
            b2 = *(const short8v*)(xbp + 64);
            b3 = *(const short8v*)(xbp + 96);
        }
        f32x4 acc0 = {0.f, 0.f, 0.f, 0.f}, acc1 = {0.f, 0.f, 0.f, 0.f};
        acc0 = __builtin_amdgcn_mfma_f32_16x16x32_bf16(a[0][0], c0, acc0, 0, 0, 0);
        acc1 = __builtin_amdgcn_mfma_f32_16x16x32_bf16(a[1][0], c0, acc1, 0, 0, 0);
        acc0 = __builtin_amdgcn_mfma_f32_16x16x32_bf16(a[0][1], c1, acc0, 0, 0, 0);
        acc1 = __builtin_amdgcn_mfma_f32_16x16x32_bf16(a[1][1], c1, acc1, 0, 0, 0);
        acc0 = __builtin_amdgcn_mfma_f32_16x16x32_bf16(a[0][2], c2, acc0, 0, 0, 0);
        acc1 = __builtin_amdgcn_mfma_f32_16x16x32_bf16(a[1][2], c2, acc1, 0, 0, 0);
        acc0 = __builtin_amdgcn_mfma_f32_16x16x32_bf16(a[0][3], c3, acc0, 0, 0, 0);
        acc1 = __builtin_amdgcn_mfma_f32_16x16x32_bf16(a[1][3], c3, acc1, 0, 0, 0);

        const int jt = jw + nt * 16;
        const int j12 = (jt - jbase) + l15;
        const int rb = l4 << 2;
#pragma unroll
        for (int p = 0; p < 4; ++p) {
            if (acc0[p] >= TAUF) {
                int row = rb + p;
                int pos = atomicAdd(&cnt[row], 1);
                if (pos < HC2) {
                    u32 key = (__float_as_uint(acc0[p]) & 0xfffff000u) | (u32)j12;
                    cand[row][pos] = key;
                    int b = keybin(key);
                    atomicAdd(&hist[row][b >> 1], (b & 1) ? 0x10000u : 1u);
                }
            }
            if (acc1[p] >= TAUF) {
                int row = 16 + rb + p;
                int pos = atomicAdd(&cnt[row], 1);
                if (pos < HC2) {
                    u32 key = (__float_as_uint(acc1[p]) & 0xfffff000u) | (u32)j12;
                    cand[row][pos] = key;
                    int b = keybin(key);
                    atomicAdd(&hist[row][b >> 1], (b & 1) ? 0x10000u : 1u);
                }
            }
        }
    }
    __syncthreads();

    const int r = tid >> 4, t = tid & 15;
    const int n = (cnt[r] < HC2) ? cnt[r] : HC2;
    const u32 K = (u32)((n < KP2) ? n : KP2);

    {
        u32 s = 0;
#pragma unroll
        for (int w = 0; w < 4; ++w) {
            u32 hw = hist[r][4 * t + w];
            s += (hw & 0xffffu) + (hw >> 16);
        }
        surv[r][t] = s;
    }
    __syncthreads();

    int B;
    {
        u32 above = 0; int t0 = -1;
#pragma unroll
        for (int u = 15; u >= 0; --u) {
            u32 pv = surv[r][u];
            if (t0 < 0) {
                if (above + pv >= K) t0 = u; else above += pv;
            }
        }
        if (t0 < 0) t0 = 0;
        int Bl = -1; u32 acc2 = above;
#pragma unroll
        for (int i = 7; i >= 0; --i) {
            int b = 8 * t0 + i;
            u32 hw = hist[r][b >> 1];
            u32 c = (b & 1) ? (hw >> 16) : (hw & 0xffffu);
            acc2 += c;
            if (Bl < 0 && acc2 >= K) Bl = b;
        }
        B = (Bl < 0) ? 0 : Bl;
    }
    __syncthreads();

    for (int p = t; p < n; p += 16) {
        u32 key = cand[r][p];
        if (keybin(key) >= B) {
            int pos = atomicAdd(&scnt[r], 1);
            if (pos < CAPW) surv[r][pos] = key;
        }
    }
    __syncthreads();

    u64* win64 = (u64*)&cand[0][0];
    {
        const int m = (scnt[r] < CAPW) ? scnt[r] : CAPW;
        const float* xir = xi[r];
#pragma unroll 1
        for (int kq = 0; kq < CAPW / 16; ++kq) {
            int c = t + 16 * kq;
            u64 outv = 0;
            if (c < m) {
                u32 key = surv[r][c];
                int j = jbase + (int)(key & 0xfffu);
                const float4* xj = (const float4*)(x_row + (size_t)j * DD);
                float s = 0.f;
#pragma unroll 4
                for (int kb = 0; kb < 32; ++kb) {
                    float4 p4 = xj[kb];
                    s = fmaf(xir[kb * 4 + 0], p4.x, s);
                    s = fmaf(xir[kb * 4 + 1], p4.y, s);
                    s = fmaf(xir[kb * 4 + 2], p4.z, s);
                    s = fmaf(xir[kb * 4 + 3], p4.w, s);
                }
                outv = packvj(s, j);
            }
            win64[r * CAPW + c] = outv;
        }
    }
    __syncthreads();

    u64* winners = (u64*)&surv[0][0];
    {
        winners[r * TOPK + t] = 0;
        winners[r * TOPK + t + 16] = 0;
        const u64* wr_ = win64 + r * CAPW;
        u64 k0 = wr_[t],      k1 = wr_[t + 16], k2 = wr_[t + 32];
        u64 k3 = wr_[t + 48], k4 = wr_[t + 64], k5 = wr_[t + 80];
        int c0 = 0, c1 = 0, c2 = 0, c3 = 0, c4 = 0, c5 = 0;
        for (int q = 0; q < CAPW; ++q) {
            u64 w = wr_[q];
            c0 += (w > k0); c1 += (w > k1); c2 += (w > k2);
            c3 += (w > k3); c4 += (w > k4); c5 += (w > k5);
        }
        if (k0 && c0 < TOPK) winners[r * TOPK + c0] = k0;
        if (k1 && c1 < TOPK) winners[r * TOPK + c1] = k1;
        if (k2 && c2 < TOPK) winners[r * TOPK + c2] = k2;
        if (k3 && c3 < TOPK) winners[r * TOPK + c3] = k3;
        if (k4 && c4 < TOPK) winners[r * TOPK + c4] = k4;
        if (k5 && c5 < TOPK) winners[r * TOPK + c5] = k5;
    }
    __syncthreads();

    for (int u = tid; u < TM2 * TOPK; u += 512) {
        int rr = u >> 5, it = u & 31;
        lists[(size_t)(i0 + rr) * 64 + h * 32 + it] = winners[rr * TOPK + it];
    }
}

// ---------- fallback merge (rank-based), aggregate + epilogue ---------------
__global__ __launch_bounds__(256) void merge_kernel(
    const float* __restrict__ s_emb, const u64* __restrict__ lists,
    const float* __restrict__ alpha_p, float* __restrict__ out_s) {
    __shared__ u64 L[RR][64];
    __shared__ u32 wjv[RR][TOPK];
    __shared__ int wj[RR][TOPK];
    const int i0 = blockIdx.x * RR;
    const int tid = threadIdx.x;

    for (int u = tid; u < RR * 64; u += 256) {
        int rr = u >> 6, p = u & 63;
        L[rr][p] = lists[(size_t)(i0 + rr) * 64 + p];
    }
    __syncthreads();

    const int r = tid >> 4, t = tid & 15;
    wjv[r][t] = 0u; wjv[r][t + 16] = 0u;
    {
        u64 k0 = L[r][t], k1 = L[r][t + 16], k2 = L[r][t + 32], k3 = L[r][t + 48];
        int c0 = 0, c1 = 0, c2 = 0, c3 = 0;
        for (int q = 0; q < 64; ++q) {
            u64 w = L[r][q];
            c0 += (w > k0); c1 += (w > k1); c2 += (w > k2); c3 += (w > k3);
        }
        if (k0 && c0 < TOPK) wjv[r][c0] = (u32)k0;
        if (k1 && c1 < TOPK) wjv[r][c1] = (u32)k1;
        if (k2 && c2 < TOPK) wjv[r][c2] = (u32)k2;
        if (k3 && c3 < TOPK) wjv[r][c3] = (u32)k3;
    }
    __syncthreads();
    {
        u32 j0 = wjv[r][t], j1 = wjv[r][t + 16];
        int s0 = 0, s1 = 0;
        for (int q = 0; q < TOPK; ++q) {
            u32 w = wjv[r][q];
            s0 += (w < j0); s1 += (w < j1);
        }
        wj[r][s0] = (int)j0;
        wj[r][s1] = (int)j1;
    }
    __syncthreads();

    const float alpha = alpha_p[0];
    const int d = tid & 127;
    for (int rp = 0; rp < 8; ++rp) {
        const int rw = rp * 2 + (tid >> 7);
        float a = 0.0f;
        for (int w = 0; w < TOPK; ++w)
            a = __fadd_rn(a, s_emb[(size_t)wj[rw][w] * DD + d]);
        float base = s_emb[(size_t)(i0 + rw) * DD + d];
        out_s[(size_t)(i0 + rw) * DD + d] = __fadd_rn(base, __fmul_rn(alpha, a));
    }
}

// ---------- queries: LDS-tiled GEMM (64 rows/block) + 2-way attention ------
__global__ __launch_bounds__(256) void query_kernel(
    const float* __restrict__ q_emb, const float* __restrict__ Wq,
    const float* __restrict__ bq, const float* __restrict__ kv,
    const float* __restrict__ alpha_p, float* __restrict__ out_q) {
    __shared__ float wqT[DD][132];
    __shared__ float qtT[DD][68];
    __shared__ float qo[64][129];
    __shared__ float a0s[64], a1s[64];
    const int row0 = blockIdx.x * 64;
    const int tid = threadIdx.x;

    for (int u = tid; u < DD * DD; u += 256) {
        int dd = u >> 7, ee = u & 127;
        wqT[ee][dd] = Wq[u];
    }
    for (int u = tid; u < 64 * DD; u += 256) {
        int ii = u >> 7, ee = u & 127;
        qtT[ee][ii] = q_emb[(size_t)row0 * DD + u];
    }
    __syncthreads();

    const int d0 = (tid & 31) * 4, i0 = (tid >> 5) * 8;
    float acc[8][4];
    {
        float b0 = bq[d0], b1 = bq[d0 + 1], b2 = bq[d0 + 2], b3 = bq[d0 + 3];
#pragma unroll
        for (int ii = 0; ii < 8; ++ii) {
            acc[ii][0] = b0; acc[ii][1] = b1; acc[ii][2] = b2; acc[ii][3] = b3;
        }
    }
    for (int e = 0; e < DD; ++e) {
        float4 wv = *(const float4*)&wqT[e][d0];
        float4 qa = *(const float4*)&qtT[e][i0];
        float4 qb = *(const float4*)&qtT[e][i0 + 4];
        float qs[8] = {qa.x, qa.y, qa.z, qa.w, qb.x, qb.y, qb.z, qb.w};
#pragma unroll
        for (int ii = 0; ii < 8; ++ii) {
            acc[ii][0] = fmaf(qs[ii], wv.x, acc[ii][0]);
            acc[ii][1] = fmaf(qs[ii], wv.y, acc[ii][1]);
            acc[ii][2] = fmaf(qs[ii], wv.z, acc[ii][2]);
            acc[ii][3] = fmaf(qs[ii], wv.w, acc[ii][3]);
        }
    }
#pragma unroll
    for (int ii = 0; ii < 8; ++ii) {
        qo[i0 + ii][d0 + 0] = acc[ii][0];
        qo[i0 + ii][d0 + 1] = acc[ii][1];
        qo[i0 + ii][d0 + 2] = acc[ii][2];
        qo[i0 + ii][d0 + 3] = acc[ii][3];
    }
    __syncthreads();
    if (tid < 64) {
        float l0 = 0.f, l1 = 0.f;
        for (int e = 0; e < DD; ++e) {
            float q = qo[tid][e];
            l0 = fmaf(q, kv[e], l0);
            l1 = fmaf(q, kv[DD + e], l1);
        }
        const float inv_scale = 0.088388347648318447f;
        l0 *= inv_scale; l1 *= inv_scale;
        float m = fmaxf(l0, l1);
        float e0 = expf(l0 - m), e1 = expf(l1 - m);
        float inv = 1.0f / (e0 + e1);
        a0s[tid] = e0 * inv; a1s[tid] = e1 * inv;
    }
    __syncthreads();
    const float alpha = alpha_p[0];
    for (int w = 0; w < 32; ++w) {
        int idx = w * 256 + tid;
        int ii = idx >> 7, dd = idx & 127;
        int gi = row0 + ii;
        if (gi < NQ - 4) {
            float ctx = a0s[ii] * kv[2 * DD + dd] + a1s[ii] * kv[3 * DD + dd];
            out_q[(size_t)gi * DD + dd] =
                __fadd_rn(q_emb[(size_t)gi * DD + dd], __fmul_rn(alpha, ctx));
        }
    }
}

// ---------- last 4 query rows (their output slots host the kv scratch) -----
__global__ __launch_bounds__(128) void query_tail_kernel(
    const float* __restrict__ q_emb, const float* __restrict__ Wq,
    const float* __restrict__ bq, const float* __restrict__ kvg,
    const float* __restrict__ alpha_p, float* __restrict__ out_q) {
    __shared__ float kvl[512];
    __shared__ float qv[DD];
    __shared__ float r0[DD], r1[DD];
    const int d = threadIdx.x;
#pragma unroll
    for (int c = 0; c < 4; ++c) kvl[c * DD + d] = kvg[c * DD + d];
    __syncthreads();

    for (int rr = 0; rr < 4; ++rr) {
        const int i = NQ - 4 + rr;
        qv[d] = q_emb[(size_t)i * DD + d];
        __syncthreads();
        float acc = bq[d];
        const float4* wr = (const float4*)(Wq + (size_t)d * DD);
#pragma unroll
        for (int c = 0; c < 32; ++c) {
            float4 w = wr[c];
            const int e = c * 4;
            acc += qv[e + 0] * w.x;
            acc += qv[e + 1] * w.y;
            acc += qv[e + 2] * w.z;
            acc += qv[e + 3] * w.w;
        }
        r0[d] = acc * kvl[d];
        r1[d] = acc * kvl[DD + d];
        __syncthreads();
#pragma unroll
        for (int s = 64; s > 0; s >>= 1) {
            if (d < s) { r0[d] += r0[d + s]; r1[d] += r1[d + s]; }
            __syncthreads();
        }
        const float inv_scale = 0.088388347648318447f;
        float l0 = r0[0] * inv_scale;
        float l1 = r1[0] * inv_scale;
        float m = fmaxf(l0, l1);
        float e0 = expf(l0 - m), e1 = expf(l1 - m);
        float inv = 1.0f / (e0 + e1);
        float a0 = e0 * inv, a1 = e1 * inv;
        float ctx = a0 * kvl[2 * DD + d] + a1 * kvl[3 * DD + d];
        float alpha = alpha_p[0];
        float res = __fadd_rn(qv[d], __fmul_rn(alpha, ctx));
        __syncthreads();
        out_q[(size_t)i * DD + d] = res;
        __syncthreads();
    }
}

extern "C" void kernel_launch(void* const* d_in, const int* in_sizes, int n_in,
                              void* d_out, int out_size, void* d_ws, size_t ws_size,
                              hipStream_t stream) {
    (void)in_sizes; (void)n_in; (void)out_size;
    const float* s_emb = (const float*)d_in[0];
    const float* q_emb = (const float*)d_in[1];
    const float* Wq = (const float*)d_in[2];
    const float* bq = (const float*)d_in[3];
    const float* Wk = (const float*)d_in[4];
    const float* bk = (const float*)d_in[5];
    const float* Wv = (const float*)d_in[6];
    const float* bv = (const float*)d_in[7];
    const float* alpha_msg  = (const float*)d_in[8];
    const float* alpha_attn = (const float*)d_in[9];
    float* out = (float*)d_out;

    float*  out_q = out + (size_t)NS * DD;                  // query outputs
    float*  x_row = out_q;                                  // 4 MB exact rows (out_q rows 0..8191)
    double* part  = (double*)(out_q + (size_t)NS * DD);     // 64 KB (out_q rows 8192..8319)
    u16*    xbf   = (u16*)(out_q + (size_t)8320 * DD);      // 2 MB bf16 copy (rows 8320..12415)
    float*  kv    = out + (size_t)(NS + NQ) * DD - 512;     // last 4 rows of out_q
    u64*    lists = (u64*)out;                              // fallback: u64 lists, row-aliased
    u32*    lists32 = (u32*)out;                            // main: u32 lists, stride 128, row-aliased

    prep_kernel<<<NS / 64, 256, 0, stream>>>(s_emb, x_row, xbf);
    proto_part_kernel<<<64, 256, 0, stream>>>(s_emb, part);
    kv_kernel<<<1, 256, 0, stream>>>(part, Wk, bk, Wv, bv, kv);
    if (d_ws != nullptr && ws_size >= WS_NEED) {
        u32* wsk = (u32*)d_ws;                              // 28.7 MB segments
        u32* wsc = wsk + (size_t)16384 * SEGSH;             // 1 MB counts
        simA_kernel<<<(NS / TM2) * 4, 512, 0, stream>>>(xbf, wsk, wsc);
        simB_kernel<<<NS / 4, 256, 0, stream>>>(x_row, wsk, wsc, lists32);
        agg_kernel<<<NS / RR, 256, 0, stream>>>(s_emb, lists32, alpha_msg, out);
    } else {
        simf_kernel<<<(NS / TM2) * 2, 512, 0, stream>>>(x_row, xbf, lists);
        merge_kernel<<<NS / RR, 256, 0, stream>>>(s_emb, lists, alpha_msg, out);
    }
    query_kernel<<<NQ / 64, 256, 0, stream>>>(q_emb, Wq, bq, kv, alpha_attn, out_q);
    query_tail_kernel<<<1, 128, 0, stream>>>(q_emb, Wq, bq, kv, alpha_attn, out_q);
}

// Round 9
// 223.301 us; speedup vs baseline: 1.1557x; 1.1557x over previous
//
#include <hip/hip_runtime.h>

typedef unsigned int u32;
typedef unsigned long long u64;
typedef unsigned short u16;

#define NS    8192
#define NQ    16384
#define DD    128
#define TOPK  32
#define RR    16

// --- MFMA-filter sim parameters (R7 geometry: best measured) ---
#define TM2   32       // rows per simA block
#define TAUF  0.1685f  // approx filter threshold (exact TAU=0.17; ~15 sigma margin vs bf16 err)
#define HC2   192      // fallback: per-half candidate cap
#define CSTR  196      // fallback: cand row stride (u32s)
#define KP2   40       // approx-top-K' target (needs 32; 8-rank margin)
#define CAPW  96       // fallback survivor cap
#define BASEK 0x3E2C8000u  // float bits floor of TAUF-masked keys
#define SEGC  44       // per-(row,half,wave) segment cap (lambda=14.5, +7.8 sigma)
#define SEGN  8        // waves per simA block
#define SEGS  (SEGC * SEGN)   // 352 slots per row-half
#define WS_NEED ((size_t)(16384 * SEGS + 16384 * SEGN) * 4 + 2048)

typedef float f32x4 __attribute__((ext_vector_type(4)));
typedef short short8v __attribute__((ext_vector_type(8)));

__device__ __forceinline__ u64 packvj(float v, int j) {
    return ((u64)__float_as_uint(v) << 32) | (u32)j;   // v>0 -> u64 order == (v, j) lex
}

__device__ __forceinline__ int keybin(u32 key) {
    u32 b = (key - BASEK) >> 19;                       // 128 bins, monotone in key
    return (b > 127u) ? 127 : (int)b;
}

// ---------- fused prep (blocks 0..127) + proto partials (blocks 128..191) ---
// prep: numpy-exact norms; row-major exact x_row + bf16 copy (bit-identical
// math to the passing version). proto: 128-col double partial sums.
__global__ __launch_bounds__(256) void prep_proto_kernel(
    const float* __restrict__ s_emb, float* __restrict__ x_row,
    u16* __restrict__ xbf, double* __restrict__ part) {
    __shared__ float tile[64][129];
    __shared__ float nrm[64];
    __shared__ double ps[256];
    const int tid = threadIdx.x;

    if (blockIdx.x < 128) {
        const int row0 = blockIdx.x * 64;
        for (int it = 0; it < 32; ++it) {
            int idx = it * 256 + tid;
            int rr = idx >> 7, cc = idx & 127;
            tile[rr][cc] = s_emb[(size_t)(row0 + rr) * DD + cc];
        }
        __syncthreads();
        if (tid < 64) {
            float r8[8];
#pragma unroll
            for (int c = 0; c < 8; ++c) { float v = tile[tid][c]; r8[c] = __fmul_rn(v, v); }
            for (int m = 1; m < 16; ++m) {
#pragma unroll
                for (int c = 0; c < 8; ++c) {
                    float v = tile[tid][8 * m + c];
                    r8[c] = __fadd_rn(r8[c], __fmul_rn(v, v));
                }
            }
            float res = __fadd_rn(
                __fadd_rn(__fadd_rn(r8[0], r8[1]), __fadd_rn(r8[2], r8[3])),
                __fadd_rn(__fadd_rn(r8[4], r8[5]), __fadd_rn(r8[6], r8[7])));
            nrm[tid] = __fsqrt_rn(res);
        }
        __syncthreads();
        for (int m = 0; m < 32; ++m) {
            int idx = m * 256 + tid;
            int rr = idx >> 7, k = idx & 127;
            float v = __fdiv_rn(tile[rr][k], nrm[rr]); // same bits as old x_t values
            x_row[(size_t)(row0 + rr) * DD + k] = v;
            u32 b = __float_as_uint(v);                // bf16 RNE
            xbf[(size_t)(row0 + rr) * DD + k] = (u16)((b + 0x7fffu + ((b >> 16) & 1u)) >> 16);
        }
    } else {
        const int b = blockIdx.x - 128;
        const int h = b >> 5, seg = b & 31;
        const int sub = tid >> 7, d = tid & 127;
        const size_t row0 = (size_t)h * 4096 + (size_t)seg * 128 + (size_t)sub * 64;
        double acc = 0.0;
        for (int r = 0; r < 64; ++r)
            acc += (double)s_emb[(row0 + r) * DD + d];
        ps[tid] = acc;
        __syncthreads();
        if (sub == 0) part[(size_t)b * DD + d] = ps[d] + ps[128 + d];
    }
}

// ---------- combine partials -> prototypes -> K,V (kv = 512 floats) --------
__global__ __launch_bounds__(256) void kv_kernel(
    const double* __restrict__ part,
    const float* __restrict__ Wk, const float* __restrict__ bk,
    const float* __restrict__ Wv, const float* __restrict__ bv,
    float* __restrict__ kv, float* __restrict__ kv2) {
    __shared__ double prd[2][DD];
    const int tid = threadIdx.x;
    const int j = tid >> 7, d = tid & 127;
    {
        const int h = (j == 0) ? 1 : 0;
        double s = 0.0;
        for (int b = 0; b < 32; ++b) s += part[(size_t)(h * 32 + b) * DD + d];
        prd[j][d] = s * (1.0 / 4096.0);
    }
    __syncthreads();
    double ka = (double)bk[d], va = (double)bv[d];
    for (int e = 0; e < DD; ++e) {
        double p = prd[j][e];
        ka += p * (double)Wk[d * DD + e];
        va += p * (double)Wv[d * DD + e];
    }
    float kf = (float)ka, vf = (float)va;
    kv[j * DD + d]          = kf;
    kv[2 * DD + j * DD + d] = vf;
    if (kv2 != nullptr) {
        kv2[j * DD + d]          = kf;
        kv2[2 * DD + j * DD + d] = vf;
    }
}

// ---------- simA: MFMA filter, ballot-prefix LDS insert, coalesced dump -----
// (R7 geometry: 512 blocks, 32 rows x one j-half, 8 waves x 512 cols)
__global__ __launch_bounds__(512) void simA_kernel(
    const u16* __restrict__ xbf, u32* __restrict__ wsk, u32* __restrict__ wsc) {
    __shared__ u32 seg[TM2 * SEGN * SEGC];              // 45,056 B, flat [row][wv][slot]
    const int tid = threadIdx.x;
    const int g = blockIdx.x >> 1, h = blockIdx.x & 1;
    const int i0 = g * TM2;
    const int jbase = h * 4096;

    const int lane = tid & 63;
    const int wv = tid >> 6;                            // 0..7
    const int l15 = lane & 15, l4 = lane >> 4;
    const int rb = l4 << 2;
    const u32 lowm = (1u << l15) - 1u;

    short8v a[2][4];
#pragma unroll
    for (int mt = 0; mt < 2; ++mt) {
        const u16* xa = xbf + (size_t)(i0 + mt * 16 + l15) * DD + (l4 << 3);
#pragma unroll
        for (int kk = 0; kk < 4; ++kk)
            a[mt][kk] = *(const short8v*)(xa + kk * 32);
    }

    int sb[8];
#pragma unroll
    for (int p = 0; p < 4; ++p) {
        sb[p]     = ((rb + p) * SEGN + wv) * SEGC;
        sb[p + 4] = ((16 + rb + p) * SEGN + wv) * SEGC;
    }
    u32 count[8];
#pragma unroll
    for (int p = 0; p < 8; ++p) count[p] = 0;

    const int jw = jbase + wv * 512;
    const u16* xbp = xbf + (size_t)(jw + l15) * DD + (l4 << 3);
    short8v b0 = *(const short8v*)(xbp);
    short8v b1 = *(const short8v*)(xbp + 32);
    short8v b2 = *(const short8v*)(xbp + 64);
    short8v b3 = *(const short8v*)(xbp + 96);
    for (int nt = 0; nt < 32; ++nt) {
        short8v c0 = b0, c1 = b1, c2 = b2, c3 = b3;
        if (nt < 31) {                                  // prefetch next 16-col tile
            xbp += 16 * DD;
            b0 = *(const short8v*)(xbp);
            b1 = *(const short8v*)(xbp + 32);
            b2 = *(const short8v*)(xbp + 64);
            b3 = *(const short8v*)(xbp + 96);
        }
        f32x4 acc0 = {0.f, 0.f, 0.f, 0.f}, acc1 = {0.f, 0.f, 0.f, 0.f};
        acc0 = __builtin_amdgcn_mfma_f32_16x16x32_bf16(a[0][0], c0, acc0, 0, 0, 0);
        acc1 = __builtin_amdgcn_mfma_f32_16x16x32_bf16(a[1][0], c0, acc1, 0, 0, 0);
        acc0 = __builtin_amdgcn_mfma_f32_16x16x32_bf16(a[0][1], c1, acc0, 0, 0, 0);
        acc1 = __builtin_amdgcn_mfma_f32_16x16x32_bf16(a[1][1], c1, acc1, 0, 0, 0);
        acc0 = __builtin_amdgcn_mfma_f32_16x16x32_bf16(a[0][2], c2, acc0, 0, 0, 0);
        acc1 = __builtin_amdgcn_mfma_f32_16x16x32_bf16(a[1][2], c2, acc1, 0, 0, 0);
        acc0 = __builtin_amdgcn_mfma_f32_16x16x32_bf16(a[0][3], c3, acc0, 0, 0, 0);
        acc1 = __builtin_amdgcn_mfma_f32_16x16x32_bf16(a[1][3], c3, acc1, 0, 0, 0);

        const u32 j12 = (u32)(wv * 512 + nt * 16 + l15);   // within-half index, 12 bits
#pragma unroll
        for (int p = 0; p < 4; ++p) {                   // C/D: col=lane&15, row=(lane>>4)*4+p
            {
                float v = acc0[p];
                bool pass = v >= TAUF;
                u64 m = __ballot(pass);
                u32 gm = (u32)(m >> (l4 << 4)) & 0xffffu;
                u32 off = count[p] + (u32)__popc(gm & lowm);
                if (pass && off < SEGC)
                    seg[sb[p] + off] = (__float_as_uint(v) & 0xfffff000u) | j12;
                count[p] += (u32)__popc(gm);
            }
            {
                float v = acc1[p];
                bool pass = v >= TAUF;
                u64 m = __ballot(pass);
                u32 gm = (u32)(m >> (l4 << 4)) & 0xffffu;
                u32 off = count[p + 4] + (u32)__popc(gm & lowm);
                if (pass && off < SEGC)
                    seg[sb[p + 4] + off] = (__float_as_uint(v) & 0xfffff000u) | j12;
                count[p + 4] += (u32)__popc(gm);
            }
        }
    }
    __syncthreads();

    if (l15 == 0) {
#pragma unroll
        for (int p = 0; p < 8; ++p) {
            int rl = (p < 4) ? (rb + p) : (16 + rb + (p - 4));
            wsc[((size_t)(h * 8192 + i0 + rl) << 3) + wv] = count[p];
        }
    }
    const size_t gbase = (size_t)(h * 8192 + i0) * (SEGN * SEGC);
    for (int u = tid; u < TM2 * SEGN * SEGC; u += 512)
        wsk[gbase + u] = seg[u];
}

// ---------- simB+agg: one WAVE per row, register-resident selection ---------
// Load 704 slots into 12 VGPRs (count-masked), uniform binary search via
// ballot counts -> threshold with count in [40,64], ballot-prefix compact
// (<=64 -> one per lane), per-lane exact ascending fmaf chain, rank among
// 64 lanes -> top-32, j-rank sort -> FUSED aggregation writes final out_s
// (same ascending-j __fadd_rn chain as the old agg kernel -> bit-identical).
__global__ __launch_bounds__(256) void simB_kernel(
    const float* __restrict__ x_row, const u32* __restrict__ wsk,
    const u32* __restrict__ wsc, const float* __restrict__ s_emb,
    const float* __restrict__ alpha_p, float* __restrict__ out_s) {
    __shared__ float xi[4][DD];                        // own row (broadcast reads)
    __shared__ u32 sj[4][64];                          // survivor j (global 0..8191)
    __shared__ u64 vals[4][64];                        // exact packed values
    __shared__ u32 win[4][TOPK];                       // rank-ordered winners (j)
    __shared__ u32 wjs[4][TOPK];                       // j-ascending winners

    const int tid = threadIdx.x;
    const int w = tid >> 6, lane = tid & 63;
    const int row = blockIdx.x * 4 + w;

    xi[w][lane] = x_row[(size_t)row * DD + lane];
    xi[w][64 + lane] = x_row[(size_t)row * DD + 64 + lane];
    if (lane < TOPK) win[w][lane] = 0u;

    // segment counts (2 halves x 8 waves), clamped
    int cw[16];
#pragma unroll
    for (int hw = 0; hw < 16; ++hw) {
        u32 c = wsc[((size_t)((hw >> 3) * 8192 + row) << 3) + (hw & 7)];
        cw[hw] = (c < (u32)SEGC) ? (int)c : SEGC;
    }

    // load all slots; invalid -> 0
    u32 k[12];
#pragma unroll
    for (int hh = 0; hh < 2; ++hh) {
        const u32* kb = wsk + (size_t)(hh * 8192 + row) * SEGS;
#pragma unroll
        for (int q = 0; q < 6; ++q) {
            int idx = q * 64 + lane;
            u32 key = 0;
            if (idx < SEGS) {
                key = kb[idx];
                int wv = (idx * 1490) >> 16;           // idx/44 for idx<352
                int s = idx - wv * 44;
                if (s >= cw[hh * 8 + wv]) key = 0;
            }
            k[hh * 6 + q] = key;
        }
    }

    // n = total valid keys
    int n = 0;
#pragma unroll
    for (int q = 0; q < 12; ++q) n += __popcll(__ballot(k[q] != 0));

    // threshold T: count(key >= T) in [min(n,40), 64]
    u32 T = 1u;
    if (n > 64) {
        u32 lo = BASEK, hi = 0x40000000u;               // count(>=lo)=n>=40, count(>=hi)=0<40
        for (int it = 0; it < 28; ++it) {
            u32 mid = (lo + hi) >> 1;
            int c = 0;
#pragma unroll
            for (int q = 0; q < 12; ++q) c += __popcll(__ballot(k[q] >= mid));
            if (c >= KP2) {
                lo = mid;
                if (c <= 64) break;                     // in window
            } else {
                hi = mid;
            }
            if (hi - lo <= 1) break;                    // collapsed: count(>=lo) ~= 40
        }
        T = lo;
    }

    // compact survivors (<= 64)
    int base = 0;
#pragma unroll
    for (int q = 0; q < 12; ++q) {
        bool pass = (k[q] >= T) && (k[q] != 0);
        u64 m = __ballot(pass);
        int pos = base + __popcll(m & ((1ull << lane) - 1ull));
        if (pass) sj[w][pos] = (u32)((q >= 6) << 12) | (k[q] & 0xfffu);
        base += __popcll(m);
    }
    const int mcnt = (base < 64) ? base : 64;

    // exact recompute: bit-identical ascending fmaf chain per lane
    u64 mine = 0;
    if (lane < mcnt) {
        int j = (int)sj[w][lane];
        const float4* xj = (const float4*)(x_row + (size_t)j * DD);
        const float* xir = xi[w];
        float s = 0.f;
#pragma unroll 4
        for (int kb = 0; kb < 32; ++kb) {
            float4 p4 = xj[kb];
            s = fmaf(xir[kb * 4 + 0], p4.x, s);
            s = fmaf(xir[kb * 4 + 1], p4.y, s);
            s = fmaf(xir[kb * 4 + 2], p4.z, s);
            s = fmaf(xir[kb * 4 + 3], p4.w, s);
        }
        mine = packvj(s, j);
    }
    vals[w][lane] = mine;

    // rank among 64 (u64 desc; broadcast LDS reads, wave-local ordering)
    int rank = 0;
#pragma unroll 8
    for (int q = 0; q < 64; ++q) rank += (vals[w][q] > mine);
    if (mine && rank < TOPK) win[w][rank] = (u32)mine;  // low 32 bits = j

    // order by j ascending via j-rank
    if (lane < TOPK) {
        u32 jv = win[w][lane];
        int s2 = 0;
#pragma unroll
        for (int q = 0; q < TOPK; ++q) s2 += (win[w][q] < jv);
        wjs[w][s2] = jv;
    }

    // fused aggregation (bit-identical to old agg kernel's chain)
    const float alpha = alpha_p[0];
    {
        float a0 = 0.f, a1 = 0.f;
        for (int q = 0; q < TOPK; ++q) {
            u32 j = wjs[w][q];
            a0 = __fadd_rn(a0, s_emb[(size_t)j * DD + lane]);
            a1 = __fadd_rn(a1, s_emb[(size_t)j * DD + 64 + lane]);
        }
        float b0 = s_emb[(size_t)row * DD + lane];
        float b1 = s_emb[(size_t)row * DD + 64 + lane];
        out_s[(size_t)row * DD + lane]      = __fadd_rn(b0, __fmul_rn(alpha, a0));
        out_s[(size_t)row * DD + 64 + lane] = __fadd_rn(b1, __fmul_rn(alpha, a1));
    }
}

// ---------- fallback fused sim kernel (used when ws too small) --------------
__global__ __launch_bounds__(512, 4) void simf_kernel(
    const float* __restrict__ x_row, const u16* __restrict__ xbf,
    u64* __restrict__ lists) {
    __shared__ __align__(16) u32 cand[TM2][CSTR];
    __shared__ __align__(16) u32 surv[TM2][CAPW];
    __shared__ u32 hist[TM2][64];
    __shared__ float xi[TM2][DD + 4];
    __shared__ int cnt[TM2];
    __shared__ int scnt[TM2];

    const int tid = threadIdx.x;
    const int g = blockIdx.x >> 1, h = blockIdx.x & 1;
    const int i0 = g * TM2;
    const int jbase = h * 4096;

    if (tid < TM2) { cnt[tid] = 0; scnt[tid] = 0; }
    for (int u = tid; u < TM2 * 64; u += 512) ((u32*)hist)[u] = 0;
    for (int u = tid; u < TM2 * DD; u += 512) {
        int r = u >> 7, k = u & 127;
        xi[r][k] = x_row[(size_t)(i0 + r) * DD + k];
    }
    __syncthreads();

    const int lane = tid & 63;
    const int wv = tid >> 6;
    const int l15 = lane & 15, l4 = lane >> 4;

    short8v a[2][4];
#pragma unroll
    for (int mt = 0; mt < 2; ++mt) {
        const u16* xa = xbf + (size_t)(i0 + mt * 16 + l15) * DD + (l4 << 3);
#pragma unroll
        for (int kk = 0; kk < 4; ++kk)
            a[mt][kk] = *(const short8v*)(xa + kk * 32);
    }

    const int jw = jbase + wv * 512;
    const u16* xbp = xbf + (size_t)(jw + l15) * DD + (l4 << 3);
    short8v b0 = *(const short8v*)(xbp);
    short8v b1 = *(const short8v*)(xbp + 32);
    short8v b2 = *(const short8v*)(xbp + 64);
    short8v b3 = *(const short8v*)(xbp + 96);
    for (int nt = 0; nt < 32; ++nt) {
        short8v c0 = b0, c1 = b1, c2 = b2, c3 = b3;
        if (nt < 31) {
            xbp += 16 * DD;
            b0 = *(const short8v*)(xbp);
            b1 = *(const short8v*)(xbp + 32);
            b2 = *(const short8v*)(xbp + 64);
            b3 = *(const short8v*)(xbp + 96);
        }
        f32x4 acc0 = {0.f, 0.f, 0.f, 0.f}, acc1 = {0.f, 0.f, 0.f, 0.f};
        acc0 = __builtin_amdgcn_mfma_f32_16x16x32_bf16(a[0][0], c0, acc0, 0, 0, 0);
        acc1 = __builtin_amdgcn_mfma_f32_16x16x32_bf16(a[1][0], c0, acc1, 0, 0, 0);
        acc0 = __builtin_amdgcn_mfma_f32_16x16x32_bf16(a[0][1], c1, acc0, 0, 0, 0);
        acc1 = __builtin_amdgcn_mfma_f32_16x16x32_bf16(a[1][1], c1, acc1, 0, 0, 0);
        acc0 = __builtin_amdgcn_mfma_f32_16x16x32_bf16(a[0][2], c2, acc0, 0, 0, 0);
        acc1 = __builtin_amdgcn_mfma_f32_16x16x32_bf16(a[1][2], c2, acc1, 0, 0, 0);
        acc0 = __builtin_amdgcn_mfma_f32_16x16x32_bf16(a[0][3], c3, acc0, 0, 0, 0);
        acc1 = __builtin_amdgcn_mfma_f32_16x16x32_bf16(a[1][3], c3, acc1, 0, 0, 0);

        const int jt = jw + nt * 16;
        const int j12 = (jt - jbase) + l15;
        const int rb = l4 << 2;
#pragma unroll
        for (int p = 0; p < 4; ++p) {
            if (acc0[p] >= TAUF) {
                int row = rb + p;
                int pos = atomicAdd(&cnt[row], 1);
                if (pos < HC2) {
                    u32 key = (__float_as_uint(acc0[p]) & 0xfffff000u) | (u32)j12;
                    cand[row][pos] = key;
                    int b = keybin(key);
                    atomicAdd(&hist[row][b >> 1], (b & 1) ? 0x10000u : 1u);
                }
            }
            if (acc1[p] >= TAUF) {
                int row = 16 + rb + p;
                int pos = atomicAdd(&cnt[row], 1);
                if (pos < HC2) {
                    u32 key = (__float_as_uint(acc1[p]) & 0xfffff000u) | (u32)j12;
                    cand[row][pos] = key;
                    int b = keybin(key);
                    atomicAdd(&hist[row][b >> 1], (b & 1) ? 0x10000u : 1u);
                }
            }
        }
    }
    __syncthreads();

    const int r = tid >> 4, t = tid & 15;
    const int n = (cnt[r] < HC2) ? cnt[r] : HC2;
    const u32 K = (u32)((n < KP2) ? n : KP2);

    {
        u32 s = 0;
#pragma unroll
        for (int w = 0; w < 4; ++w) {
            u32 hw = hist[r][4 * t + w];
            s += (hw & 0xffffu) + (hw >> 16);
        }
        surv[r][t] = s;
    }
    __syncthreads();

    int B;
    {
        u32 above = 0; int t0 = -1;
#pragma unroll
        for (int u = 15; u >= 0; --u) {
            u32 pv = surv[r][u];
            if (t0 < 0) {
                if (above + pv >= K) t0 = u; else above += pv;
            }
        }
        if (t0 < 0) t0 = 0;
        int Bl = -1; u32 acc2 = above;
#pragma unroll
        for (int i = 7; i >= 0; --i) {
            int b = 8 * t0 + i;
            u32 hw = hist[r][b >> 1];
            u32 c = (b & 1) ? (hw >> 16) : (hw & 0xffffu);
            acc2 += c;
            if (Bl < 0 && acc2 >= K) Bl = b;
        }
        B = (Bl < 0) ? 0 : Bl;
    }
    __syncthreads();

    for (int p = t; p < n; p += 16) {
        u32 key = cand[r][p];
        if (keybin(key) >= B) {
            int pos = atomicAdd(&scnt[r], 1);
            if (pos < CAPW) surv[r][pos] = key;
        }
    }
    __syncthreads();

    u64* win64 = (u64*)&cand[0][0];
    {
        const int m = (scnt[r] < CAPW) ? scnt[r] : CAPW;
        const float* xir = xi[r];
#pragma unroll 1
        for (int kq = 0; kq < CAPW / 16; ++kq) {
            int c = t + 16 * kq;
            u64 outv = 0;
            if (c < m) {
                u32 key = surv[r][c];
                int j = jbase + (int)(key & 0xfffu);
                const float4* xj = (const float4*)(x_row + (size_t)j * DD);
                float s = 0.f;
#pragma unroll 4
                for (int kb = 0; kb < 32; ++kb) {
                    float4 p4 = xj[kb];
                    s = fmaf(xir[kb * 4 + 0], p4.x, s);
                    s = fmaf(xir[kb * 4 + 1], p4.y, s);
                    s = fmaf(xir[kb * 4 + 2], p4.z, s);
                    s = fmaf(xir[kb * 4 + 3], p4.w, s);
                }
                outv = packvj(s, j);
            }
            win64[r * CAPW + c] = outv;
        }
    }
    __syncthreads();

    u64* winners = (u64*)&surv[0][0];
    {
        winners[r * TOPK + t] = 0;
        winners[r * TOPK + t + 16] = 0;
        const u64* wr_ = win64 + r * CAPW;
        u64 k0 = wr_[t],      k1 = wr_[t + 16], k2 = wr_[t + 32];
        u64 k3 = wr_[t + 48], k4 = wr_[t + 64], k5 = wr_[t + 80];
        int c0 = 0, c1 = 0, c2 = 0, c3 = 0, c4 = 0, c5 = 0;
        for (int q = 0; q < CAPW; ++q) {
            u64 w = wr_[q];
            c0 += (w > k0); c1 += (w > k1); c2 += (w > k2);
            c3 += (w > k3); c4 += (w > k4); c5 += (w > k5);
        }
        if (k0 && c0 < TOPK) winners[r * TOPK + c0] = k0;
        if (k1 && c1 < TOPK) winners[r * TOPK + c1] = k1;
        if (k2 && c2 < TOPK) winners[r * TOPK + c2] = k2;
        if (k3 && c3 < TOPK) winners[r * TOPK + c3] = k3;
        if (k4 && c4 < TOPK) winners[r * TOPK + c4] = k4;
        if (k5 && c5 < TOPK) winners[r * TOPK + c5] = k5;
    }
    __syncthreads();

    for (int u = tid; u < TM2 * TOPK; u += 512) {
        int rr = u >> 5, it = u & 31;
        lists[(size_t)(i0 + rr) * 64 + h * 32 + it] = winners[rr * TOPK + it];
    }
}

// ---------- fallback merge (rank-based), aggregate + epilogue ---------------
__global__ __launch_bounds__(256) void merge_kernel(
    const float* __restrict__ s_emb, const u64* __restrict__ lists,
    const float* __restrict__ alpha_p, float* __restrict__ out_s) {
    __shared__ u64 L[RR][64];
    __shared__ u32 wjv[RR][TOPK];
    __shared__ int wj[RR][TOPK];
    const int i0 = blockIdx.x * RR;
    const int tid = threadIdx.x;

    for (int u = tid; u < RR * 64; u += 256) {
        int rr = u >> 6, p = u & 63;
        L[rr][p] = lists[(size_t)(i0 + rr) * 64 + p];
    }
    __syncthreads();

    const int r = tid >> 4, t = tid & 15;
    wjv[r][t] = 0u; wjv[r][t + 16] = 0u;
    {
        u64 k0 = L[r][t], k1 = L[r][t + 16], k2 = L[r][t + 32], k3 = L[r][t + 48];
        int c0 = 0, c1 = 0, c2 = 0, c3 = 0;
        for (int q = 0; q < 64; ++q) {
            u64 w = L[r][q];
            c0 += (w > k0); c1 += (w > k1); c2 += (w > k2); c3 += (w > k3);
        }
        if (k0 && c0 < TOPK) wjv[r][c0] = (u32)k0;
        if (k1 && c1 < TOPK) wjv[r][c1] = (u32)k1;
        if (k2 && c2 < TOPK) wjv[r][c2] = (u32)k2;
        if (k3 && c3 < TOPK) wjv[r][c3] = (u32)k3;
    }
    __syncthreads();
    {
        u32 j0 = wjv[r][t], j1 = wjv[r][t + 16];
        int s0 = 0, s1 = 0;
        for (int q = 0; q < TOPK; ++q) {
            u32 w = wjv[r][q];
            s0 += (w < j0); s1 += (w < j1);
        }
        wj[r][s0] = (int)j0;
        wj[r][s1] = (int)j1;
    }
    __syncthreads();

    const float alpha = alpha_p[0];
    const int d = tid & 127;
    for (int rp = 0; rp < 8; ++rp) {
        const int rw = rp * 2 + (tid >> 7);
        float a = 0.0f;
        for (int w = 0; w < TOPK; ++w)
            a = __fadd_rn(a, s_emb[(size_t)wj[rw][w] * DD + d]);
        float base = s_emb[(size_t)(i0 + rw) * DD + d];
        out_s[(size_t)(i0 + rw) * DD + d] = __fadd_rn(base, __fmul_rn(alpha, a));
    }
}

// ---------- queries: LDS-tiled GEMM (64 rows/block) + 2-way attention ------
// Reads kv from kvp (non-aliased kv2 in main path -> covers all nq_limit rows).
__global__ __launch_bounds__(256) void query_kernel(
    const float* __restrict__ q_emb, const float* __restrict__ Wq,
    const float* __restrict__ bq, const float* __restrict__ kvp,
    const float* __restrict__ alpha_p, float* __restrict__ out_q,
    int nq_limit) {
    __shared__ float wqT[DD][132];
    __shared__ float qtT[DD][68];
    __shared__ float qo[64][129];
    __shared__ float a0s[64], a1s[64];
    __shared__ float kvl[512];
    const int row0 = blockIdx.x * 64;
    const int tid = threadIdx.x;

    for (int u = tid; u < 512; u += 256) kvl[u] = kvp[u];
    for (int u = tid; u < DD * DD; u += 256) {
        int dd = u >> 7, ee = u & 127;
        wqT[ee][dd] = Wq[u];
    }
    for (int u = tid; u < 64 * DD; u += 256) {
        int ii = u >> 7, ee = u & 127;
        qtT[ee][ii] = q_emb[(size_t)row0 * DD + u];
    }
    __syncthreads();

    const int d0 = (tid & 31) * 4, i0 = (tid >> 5) * 8;
    float acc[8][4];
    {
        float b0 = bq[d0], b1 = bq[d0 + 1], b2 = bq[d0 + 2], b3 = bq[d0 + 3];
#pragma unroll
        for (int ii = 0; ii < 8; ++ii) {
            acc[ii][0] = b0; acc[ii][1] = b1; acc[ii][2] = b2; acc[ii][3] = b3;
        }
    }
    for (int e = 0; e < DD; ++e) {
        float4 wv = *(const float4*)&wqT[e][d0];
        float4 qa = *(const float4*)&qtT[e][i0];
        float4 qb = *(const float4*)&qtT[e][i0 + 4];
        float qs[8] = {qa.x, qa.y, qa.z, qa.w, qb.x, qb.y, qb.z, qb.w};
#pragma unroll
        for (int ii = 0; ii < 8; ++ii) {
            acc[ii][0] = fmaf(qs[ii], wv.x, acc[ii][0]);
            acc[ii][1] = fmaf(qs[ii], wv.y, acc[ii][1]);
            acc[ii][2] = fmaf(qs[ii], wv.z, acc[ii][2]);
            acc[ii][3] = fmaf(qs[ii], wv.w, acc[ii][3]);
        }
    }
#pragma unroll
    for (int ii = 0; ii < 8; ++ii) {
        qo[i0 + ii][d0 + 0] = acc[ii][0];
        qo[i0 + ii][d0 + 1] = acc[ii][1];
        qo[i0 + ii][d0 + 2] = acc[ii][2];
        qo[i0 + ii][d0 + 3] = acc[ii][3];
    }
    __syncthreads();
    if (tid < 64) {
        float l0 = 0.f, l1 = 0.f;
        for (int e = 0; e < DD; ++e) {
            float q = qo[tid][e];
            l0 = fmaf(q, kvl[e], l0);
            l1 = fmaf(q, kvl[DD + e], l1);
        }
        const float inv_scale = 0.088388347648318447f;
        l0 *= inv_scale; l1 *= inv_scale;
        float m = fmaxf(l0, l1);
        float e0 = expf(l0 - m), e1 = expf(l1 - m);
        float inv = 1.0f / (e0 + e1);
        a0s[tid] = e0 * inv; a1s[tid] = e1 * inv;
    }
    __syncthreads();
    const float alpha = alpha_p[0];
    for (int w = 0; w < 32; ++w) {
        int idx = w * 256 + tid;
        int ii = idx >> 7, dd = idx & 127;
        int gi = row0 + ii;
        if (gi < nq_limit) {
            float ctx = a0s[ii] * kvl[2 * DD + dd] + a1s[ii] * kvl[3 * DD + dd];
            out_q[(size_t)gi * DD + dd] =
                __fadd_rn(q_emb[(size_t)gi * DD + dd], __fmul_rn(alpha, ctx));
        }
    }
}

// ---------- fallback-only: last 4 query rows (kv scratch lives there) -------
__global__ __launch_bounds__(128) void query_tail_kernel(
    const float* __restrict__ q_emb, const float* __restrict__ Wq,
    const float* __restrict__ bq, const float* __restrict__ kvg,
    const float* __restrict__ alpha_p, float* __restrict__ out_q) {
    __shared__ float kvl[512];
    __shared__ float qv[DD];
    __shared__ float r0[DD], r1[DD];
    const int d = threadIdx.x;
#pragma unroll
    for (int c = 0; c < 4; ++c) kvl[c * DD + d] = kvg[c * DD + d];
    __syncthreads();

    for (int rr = 0; rr < 4; ++rr) {
        const int i = NQ - 4 + rr;
        qv[d] = q_emb[(size_t)i * DD + d];
        __syncthreads();
        float acc = bq[d];
        const float4* wr = (const float4*)(Wq + (size_t)d * DD);
#pragma unroll
        for (int c = 0; c < 32; ++c) {
            float4 w = wr[c];
            const int e = c * 4;
            acc += qv[e + 0] * w.x;
            acc += qv[e + 1] * w.y;
            acc += qv[e + 2] * w.z;
            acc += qv[e + 3] * w.w;
        }
        r0[d] = acc * kvl[d];
        r1[d] = acc * kvl[DD + d];
        __syncthreads();
#pragma unroll
        for (int s = 64; s > 0; s >>= 1) {
            if (d < s) { r0[d] += r0[d + s]; r1[d] += r1[d + s]; }
            __syncthreads();
        }
        const float inv_scale = 0.088388347648318447f;
        float l0 = r0[0] * inv_scale;
        float l1 = r1[0] * inv_scale;
        float m = fmaxf(l0, l1);
        float e0 = expf(l0 - m), e1 = expf(l1 - m);
        float inv = 1.0f / (e0 + e1);
        float a0 = e0 * inv, a1 = e1 * inv;
        float ctx = a0 * kvl[2 * DD + d] + a1 * kvl[3 * DD + d];
        float alpha = alpha_p[0];
        float res = __fadd_rn(qv[d], __fmul_rn(alpha, ctx));
        __syncthreads();
        out_q[(size_t)i * DD + d] = res;
        __syncthreads();
    }
}

extern "C" void kernel_launch(void* const* d_in, const int* in_sizes, int n_in,
                              void* d_out, int out_size, void* d_ws, size_t ws_size,
                              hipStream_t stream) {
    (void)in_sizes; (void)n_in; (void)out_size;
    const float* s_emb = (const float*)d_in[0];
    const float* q_emb = (const float*)d_in[1];
    const float* Wq = (const float*)d_in[2];
    const float* bq = (const float*)d_in[3];
    const float* Wk = (const float*)d_in[4];
    const float* bk = (const float*)d_in[5];
    const float* Wv = (const float*)d_in[6];
    const float* bv = (const float*)d_in[7];
    const float* alpha_msg  = (const float*)d_in[8];
    const float* alpha_attn = (const float*)d_in[9];
    float* out = (float*)d_out;

    float*  out_q = out + (size_t)NS * DD;                  // query outputs
    float*  x_row = out_q;                                  // 4 MB exact rows (out_q rows 0..8191)
    double* part  = (double*)(out_q + (size_t)NS * DD);     // 64 KB (out_q rows 8192..8319)
    u16*    xbf   = (u16*)(out_q + (size_t)8320 * DD);      // 2 MB bf16 copy (rows 8320..12415)
    float*  kv    = out + (size_t)(NS + NQ) * DD - 512;     // last 4 rows of out_q
    u64*    lists = (u64*)out;                              // fallback: u64 lists, row-aliased

    const bool use_ws = (d_ws != nullptr && ws_size >= WS_NEED);
    u32* wsk = (u32*)d_ws;                                  // 23.1 MB segments
    u32* wsc = use_ws ? wsk + (size_t)16384 * SEGS : nullptr;
    float* kv2 = use_ws ? (float*)(wsc + (size_t)16384 * SEGN) : nullptr;

    prep_proto_kernel<<<192, 256, 0, stream>>>(s_emb, x_row, xbf, part);
    kv_kernel<<<1, 256, 0, stream>>>(part, Wk, bk, Wv, bv, kv, kv2);
    if (use_ws) {
        simA_kernel<<<(NS / TM2) * 2, 512, 0, stream>>>(xbf, wsk, wsc);
        simB_kernel<<<NS / 4, 256, 0, stream>>>(x_row, wsk, wsc, s_emb, alpha_msg, out);
        query_kernel<<<NQ / 64, 256, 0, stream>>>(q_emb, Wq, bq, kv2, alpha_attn, out_q, NQ);
    } else {
        simf_kernel<<<(NS / TM2) * 2, 512, 0, stream>>>(x_row, xbf, lists);
        merge_kernel<<<NS / RR, 256, 0, stream>>>(s_emb, lists, alpha_msg, out);
        query_kernel<<<NQ / 64, 256, 0, stream>>>(q_emb, Wq, bq, kv, alpha_attn, out_q, NQ - 4);
        query_tail_kernel<<<1, 128, 0, stream>>>(q_emb, Wq, bq, kv, alpha_attn, out_q);
    }
}